// Round 4
// baseline (108.044 us; speedup 1.0000x reference)
//
#include <hip/hip_runtime.h>

constexpr int D = 20;

typedef float f4 __attribute__((ext_vector_type(4)));

// Block-specialized fused kernel with nontemporal streaming:
//   even blocks -> per-row job (gather z, scalar heads)
//   odd  blocks -> flat coalesced fill of x_logits0/1
// All zero-reuse streams use nt loads/stores so the 16.8 MB qz tables stay
// resident in L2/L3 and the random gather stays a cache hit.
__global__ __launch_bounds__(256) void cevae_fused3_kernel(
    const float* __restrict__ x, const float* __restrict__ t,
    const float* __restrict__ y, const float* __restrict__ qz_w,
    const float* __restrict__ qz_b,
    const float* __restrict__ dx_w, const float* __restrict__ dx_b,
    const float* __restrict__ sc_tw, const float* __restrict__ sc_tb,
    const float* __restrict__ sc_y0w, const float* __restrict__ sc_y0b,
    const float* __restrict__ sc_y1w, const float* __restrict__ sc_y1b,
    const float* __restrict__ pz, float* __restrict__ out, int n_rows,
    int n_fb)
{
    int bid = blockIdx.x;
    if ((bid & 1) == 0) {
        // ---------------- rows job ----------------
        int n = (bid >> 1) * 256 + threadIdx.x;
        if (n >= n_rows) return;

        const f4* xr = (const f4*)(x + (size_t)n * D);
        f4 a = __builtin_nontemporal_load(xr + 0);
        f4 b = __builtin_nontemporal_load(xr + 1);
        f4 c = __builtin_nontemporal_load(xr + 2);
        f4 d = __builtin_nontemporal_load(xr + 3);
        f4 e = __builtin_nontemporal_load(xr + 4);
        float tv = __builtin_nontemporal_load(t + n);
        float yv = __builtin_nontemporal_load(y + n);

        unsigned idx = (tv != 0.0f) ? (1u << 20) : 0u;
        idx |= ((unsigned)a.x) << 19;
        idx |= ((unsigned)a.y) << 18;
        idx |= ((unsigned)a.z) << 17;
        idx |= ((unsigned)a.w) << 16;
        idx |= ((unsigned)b.x) << 15;
        idx |= ((unsigned)b.y) << 14;
        idx |= ((unsigned)b.z) << 13;
        idx |= ((unsigned)b.w) << 12;
        idx |= ((unsigned)c.x) << 11;
        idx |= ((unsigned)c.y) << 10;
        idx |= ((unsigned)c.z) << 9;
        idx |= ((unsigned)c.w) << 8;
        idx |= ((unsigned)d.x) << 7;
        idx |= ((unsigned)d.y) << 6;
        idx |= ((unsigned)d.z) << 5;
        idx |= ((unsigned)d.w) << 4;
        idx |= ((unsigned)e.x) << 3;
        idx |= ((unsigned)e.y) << 2;
        idx |= ((unsigned)e.z) << 1;
        idx |= ((unsigned)e.w);

        // gather: CACHEABLE loads (tables must stay L2/L3 resident)
        float z = fmaf(qz_w[idx], yv, qz_b[idx]);
        __builtin_nontemporal_store(z, out + n);

        float tw  = *sc_tw,  tb  = *sc_tb;
        float y0w = *sc_y0w, y0b = *sc_y0b;
        float y1w = *sc_y1w, y1b = *sc_y1b;

        // layout: [z(N)][xl0(N*D)][xl1(N*D)][t0(N)][t1(N)][y0(N)][y1(N)][pz(1)]
        size_t o3 = (size_t)n_rows * (size_t)(1 + 2 * D);
        __builtin_nontemporal_store(tb, out + o3 + n);
        __builtin_nontemporal_store(tw + tb, out + o3 + (size_t)n_rows + n);
        __builtin_nontemporal_store(fmaf(tv, y1b - y0b, y0b),
                                    out + o3 + 2 * (size_t)n_rows + n);
        __builtin_nontemporal_store(fmaf(tv, (y1w + y1b) - (y0w + y0b), y0w + y0b),
                                    out + o3 + 3 * (size_t)n_rows + n);
        if (n == 0) out[o3 + 4 * (size_t)n_rows] = pz[0];
    } else {
        // ---------------- fill job (coalesced flat nt float4 stores) ----------------
        size_t Q = (size_t)n_rows * D / 4;          // float4 count per region
        f4* r0 = (f4*)(out + n_rows);               // x_logits0
        f4* r1 = r0 + Q;                            // x_logits1
        size_t stride = (size_t)n_fb * 256;
        size_t q0 = (size_t)(bid >> 1) * 256 + threadIdx.x;
        for (size_t q = q0; q < Q; q += stride) {
            int cb = (int)(q % 5) * 4;              // column base 0,4,8,12,16
            float b0 = dx_b[cb + 0], b1 = dx_b[cb + 1];
            float b2 = dx_b[cb + 2], b3 = dx_b[cb + 3];
            float w0 = dx_w[cb + 0], w1 = dx_w[cb + 1];
            float w2 = dx_w[cb + 2], w3 = dx_w[cb + 3];
            f4 v0 = {b0, b1, b2, b3};
            f4 v1 = {w0 + b0, w1 + b1, w2 + b2, w3 + b3};
            __builtin_nontemporal_store(v0, r0 + q);
            __builtin_nontemporal_store(v1, r1 + q);
        }
    }
}

extern "C" void kernel_launch(void* const* d_in, const int* in_sizes, int n_in,
                              void* d_out, int out_size, void* d_ws, size_t ws_size,
                              hipStream_t stream) {
    const float* x    = (const float*)d_in[0];
    const float* t    = (const float*)d_in[1];
    const float* y    = (const float*)d_in[2];
    const float* qz_w = (const float*)d_in[3];
    const float* qz_b = (const float*)d_in[4];
    const float* dx_w = (const float*)d_in[5];
    const float* dx_b = (const float*)d_in[6];
    const float* t_w  = (const float*)d_in[7];
    const float* t_b  = (const float*)d_in[8];
    const float* y0_w = (const float*)d_in[9];
    const float* y0_b = (const float*)d_in[10];
    const float* y1_w = (const float*)d_in[11];
    const float* y1_b = (const float*)d_in[12];
    const float* pz   = (const float*)d_in[13];
    float* out = (float*)d_out;

    int n_rows = in_sizes[0] / D;            // 1,000,000
    int n_rb = (n_rows + 255) / 256;         // 3907 rows blocks
    int n_fb = n_rb;                         // 3907 fill blocks (grid-stride)

    cevae_fused3_kernel<<<2 * n_rb, 256, 0, stream>>>(
        x, t, y, qz_w, qz_b, dx_w, dx_b, t_w, t_b, y0_w, y0_b, y1_w, y1_b,
        pz, out, n_rows, n_fb);
}

// Round 5
// 82.398 us; speedup vs baseline: 1.3113x; 1.3113x over previous
//
#include <hip/hip_runtime.h>

constexpr int D = 20;

typedef float f4 __attribute__((ext_vector_type(4)));

// Block-specialized fused kernel. Roles assigned in groups of 8 consecutive
// blocks so BOTH roles round-robin evenly across the 8 XCDs (role=(bid>>3)&1).
//   groups: [8 rows blocks][8 fill blocks][8 rows]...
//   rows job: gather z + scalar heads (coalesced reads, random table gather)
//   fill job: flat coalesced float4 fill of x_logits0/1
__global__ __launch_bounds__(256) void cevae_fused4_kernel(
    const float* __restrict__ x, const float* __restrict__ t,
    const float* __restrict__ y, const float* __restrict__ qz_w,
    const float* __restrict__ qz_b,
    const float* __restrict__ dx_w, const float* __restrict__ dx_b,
    const float* __restrict__ sc_tw, const float* __restrict__ sc_tb,
    const float* __restrict__ sc_y0w, const float* __restrict__ sc_y0b,
    const float* __restrict__ sc_y1w, const float* __restrict__ sc_y1b,
    const float* __restrict__ pz, float* __restrict__ out, int n_rows,
    int n_job_blocks)
{
    int bid = blockIdx.x;
    int sub = ((bid >> 4) << 3) | (bid & 7);   // block index within its role
    if (((bid >> 3) & 1) == 0) {
        // ---------------- rows job ----------------
        int n = sub * 256 + threadIdx.x;
        if (n >= n_rows) return;

        const f4* xr = (const f4*)(x + (size_t)n * D);
        f4 a = xr[0];
        f4 b = xr[1];
        f4 c = xr[2];
        f4 d = xr[3];
        f4 e = xr[4];
        float tv = t[n];
        float yv = y[n];

        unsigned idx = (tv != 0.0f) ? (1u << 20) : 0u;
        idx |= ((unsigned)a.x) << 19;
        idx |= ((unsigned)a.y) << 18;
        idx |= ((unsigned)a.z) << 17;
        idx |= ((unsigned)a.w) << 16;
        idx |= ((unsigned)b.x) << 15;
        idx |= ((unsigned)b.y) << 14;
        idx |= ((unsigned)b.z) << 13;
        idx |= ((unsigned)b.w) << 12;
        idx |= ((unsigned)c.x) << 11;
        idx |= ((unsigned)c.y) << 10;
        idx |= ((unsigned)c.z) << 9;
        idx |= ((unsigned)c.w) << 8;
        idx |= ((unsigned)d.x) << 7;
        idx |= ((unsigned)d.y) << 6;
        idx |= ((unsigned)d.z) << 5;
        idx |= ((unsigned)d.w) << 4;
        idx |= ((unsigned)e.x) << 3;
        idx |= ((unsigned)e.y) << 2;
        idx |= ((unsigned)e.z) << 1;
        idx |= ((unsigned)e.w);

        float z = fmaf(qz_w[idx], yv, qz_b[idx]);
        out[n] = z;

        float tw  = *sc_tw,  tb  = *sc_tb;
        float y0w = *sc_y0w, y0b = *sc_y0b;
        float y1w = *sc_y1w, y1b = *sc_y1b;

        // layout: [z(N)][xl0(N*D)][xl1(N*D)][t0(N)][t1(N)][y0(N)][y1(N)][pz(1)]
        size_t o3 = (size_t)n_rows * (size_t)(1 + 2 * D);
        out[o3 + n] = tb;
        out[o3 + (size_t)n_rows + n] = tw + tb;
        out[o3 + 2 * (size_t)n_rows + n] = fmaf(tv, y1b - y0b, y0b);
        out[o3 + 3 * (size_t)n_rows + n] = fmaf(tv, (y1w + y1b) - (y0w + y0b), y0w + y0b);
        if (n == 0) out[o3 + 4 * (size_t)n_rows] = pz[0];
    } else {
        // ---------------- fill job (coalesced flat float4 stores) ----------------
        size_t Q = (size_t)n_rows * D / 4;          // float4 count per region
        f4* r0 = (f4*)(out + n_rows);               // x_logits0
        f4* r1 = r0 + Q;                            // x_logits1
        size_t stride = (size_t)n_job_blocks * 256;
        size_t q0 = (size_t)sub * 256 + threadIdx.x;
        for (size_t q = q0; q < Q; q += stride) {
            int cb = (int)(q % 5) * 4;              // column base 0,4,8,12,16
            float b0 = dx_b[cb + 0], b1 = dx_b[cb + 1];
            float b2 = dx_b[cb + 2], b3 = dx_b[cb + 3];
            float w0 = dx_w[cb + 0], w1 = dx_w[cb + 1];
            float w2 = dx_w[cb + 2], w3 = dx_w[cb + 3];
            f4 v0 = {b0, b1, b2, b3};
            f4 v1 = {w0 + b0, w1 + b1, w2 + b2, w3 + b3};
            r0[q] = v0;
            r1[q] = v1;
        }
    }
}

extern "C" void kernel_launch(void* const* d_in, const int* in_sizes, int n_in,
                              void* d_out, int out_size, void* d_ws, size_t ws_size,
                              hipStream_t stream) {
    const float* x    = (const float*)d_in[0];
    const float* t    = (const float*)d_in[1];
    const float* y    = (const float*)d_in[2];
    const float* qz_w = (const float*)d_in[3];
    const float* qz_b = (const float*)d_in[4];
    const float* dx_w = (const float*)d_in[5];
    const float* dx_b = (const float*)d_in[6];
    const float* t_w  = (const float*)d_in[7];
    const float* t_b  = (const float*)d_in[8];
    const float* y0_w = (const float*)d_in[9];
    const float* y0_b = (const float*)d_in[10];
    const float* y1_w = (const float*)d_in[11];
    const float* y1_b = (const float*)d_in[12];
    const float* pz   = (const float*)d_in[13];
    float* out = (float*)d_out;

    int n_rows = in_sizes[0] / D;            // 1,000,000
    int n_rb = (n_rows + 255) / 256;         // 3907 rows blocks needed
    int n_groups = (n_rb + 7) / 8;           // groups of 8 blocks per role
    int n_job_blocks = n_groups * 8;         // blocks per role (rows & fill)

    cevae_fused4_kernel<<<n_groups * 16, 256, 0, stream>>>(
        x, t, y, qz_w, qz_b, dx_w, dx_b, t_w, t_b, y0_w, y0_b, y1_w, y1_b,
        pz, out, n_rows, n_job_blocks);
}

// Round 6
// 78.902 us; speedup vs baseline: 1.3693x; 1.0443x over previous
//
#include <hip/hip_runtime.h>

constexpr int D = 20;

typedef float f4 __attribute__((ext_vector_type(4)));

// Pass 1: interleave qz_w/qz_b into float2 so each row's gather is ONE random
// 64B-line request instead of two. Coalesced build, ~34 MB traffic, ~4 us.
__global__ __launch_bounds__(256) void cevae_build_wb(
    const float* __restrict__ qz_w, const float* __restrict__ qz_b,
    float2* __restrict__ wb, int nc)
{
    int stride = gridDim.x * 256;
    for (int i = blockIdx.x * 256 + threadIdx.x; i < nc; i += stride)
        wb[i] = make_float2(qz_w[i], qz_b[i]);
}

// Pass 2: block-specialized fused kernel. Roles in groups of 8 consecutive
// blocks so both roles round-robin evenly across the 8 XCDs.
//   rows job: single float2 gather for z + scalar heads
//   fill job: flat coalesced float4 fill of x_logits0/1
template <bool USE_WB>
__global__ __launch_bounds__(256) void cevae_fused5_kernel(
    const float* __restrict__ x, const float* __restrict__ t,
    const float* __restrict__ y, const float2* __restrict__ wb,
    const float* __restrict__ qz_w, const float* __restrict__ qz_b,
    const float* __restrict__ dx_w, const float* __restrict__ dx_b,
    const float* __restrict__ sc_tw, const float* __restrict__ sc_tb,
    const float* __restrict__ sc_y0w, const float* __restrict__ sc_y0b,
    const float* __restrict__ sc_y1w, const float* __restrict__ sc_y1b,
    const float* __restrict__ pz, float* __restrict__ out, int n_rows,
    int n_job_blocks)
{
    int bid = blockIdx.x;
    int sub = ((bid >> 4) << 3) | (bid & 7);   // block index within its role
    if (((bid >> 3) & 1) == 0) {
        // ---------------- rows job ----------------
        int n = sub * 256 + threadIdx.x;
        if (n >= n_rows) return;

        const f4* xr = (const f4*)(x + (size_t)n * D);
        f4 a = xr[0];
        f4 b = xr[1];
        f4 c = xr[2];
        f4 d = xr[3];
        f4 e = xr[4];
        float tv = t[n];
        float yv = y[n];

        unsigned idx = (tv != 0.0f) ? (1u << 20) : 0u;
        idx |= ((unsigned)a.x) << 19;
        idx |= ((unsigned)a.y) << 18;
        idx |= ((unsigned)a.z) << 17;
        idx |= ((unsigned)a.w) << 16;
        idx |= ((unsigned)b.x) << 15;
        idx |= ((unsigned)b.y) << 14;
        idx |= ((unsigned)b.z) << 13;
        idx |= ((unsigned)b.w) << 12;
        idx |= ((unsigned)c.x) << 11;
        idx |= ((unsigned)c.y) << 10;
        idx |= ((unsigned)c.z) << 9;
        idx |= ((unsigned)c.w) << 8;
        idx |= ((unsigned)d.x) << 7;
        idx |= ((unsigned)d.y) << 6;
        idx |= ((unsigned)d.z) << 5;
        idx |= ((unsigned)d.w) << 4;
        idx |= ((unsigned)e.x) << 3;
        idx |= ((unsigned)e.y) << 2;
        idx |= ((unsigned)e.z) << 1;
        idx |= ((unsigned)e.w);

        float z;
        if (USE_WB) {
            float2 wv = wb[idx];                 // ONE random line request
            z = fmaf(wv.x, yv, wv.y);
        } else {
            z = fmaf(qz_w[idx], yv, qz_b[idx]);  // fallback: two requests
        }
        out[n] = z;

        float tw  = *sc_tw,  tb  = *sc_tb;
        float y0w = *sc_y0w, y0b = *sc_y0b;
        float y1w = *sc_y1w, y1b = *sc_y1b;

        // layout: [z(N)][xl0(N*D)][xl1(N*D)][t0(N)][t1(N)][y0(N)][y1(N)][pz(1)]
        size_t o3 = (size_t)n_rows * (size_t)(1 + 2 * D);
        out[o3 + n] = tb;
        out[o3 + (size_t)n_rows + n] = tw + tb;
        out[o3 + 2 * (size_t)n_rows + n] = fmaf(tv, y1b - y0b, y0b);
        out[o3 + 3 * (size_t)n_rows + n] = fmaf(tv, (y1w + y1b) - (y0w + y0b), y0w + y0b);
        if (n == 0) out[o3 + 4 * (size_t)n_rows] = pz[0];
    } else {
        // ---------------- fill job (coalesced flat float4 stores) ----------------
        size_t Q = (size_t)n_rows * D / 4;          // float4 count per region
        f4* r0 = (f4*)(out + n_rows);               // x_logits0
        f4* r1 = r0 + Q;                            // x_logits1
        size_t stride = (size_t)n_job_blocks * 256;
        size_t q0 = (size_t)sub * 256 + threadIdx.x;
        for (size_t q = q0; q < Q; q += stride) {
            int cb = (int)(q % 5) * 4;              // column base 0,4,8,12,16
            float b0 = dx_b[cb + 0], b1 = dx_b[cb + 1];
            float b2 = dx_b[cb + 2], b3 = dx_b[cb + 3];
            float w0 = dx_w[cb + 0], w1 = dx_w[cb + 1];
            float w2 = dx_w[cb + 2], w3 = dx_w[cb + 3];
            f4 v0 = {b0, b1, b2, b3};
            f4 v1 = {w0 + b0, w1 + b1, w2 + b2, w3 + b3};
            r0[q] = v0;
            r1[q] = v1;
        }
    }
}

extern "C" void kernel_launch(void* const* d_in, const int* in_sizes, int n_in,
                              void* d_out, int out_size, void* d_ws, size_t ws_size,
                              hipStream_t stream) {
    const float* x    = (const float*)d_in[0];
    const float* t    = (const float*)d_in[1];
    const float* y    = (const float*)d_in[2];
    const float* qz_w = (const float*)d_in[3];
    const float* qz_b = (const float*)d_in[4];
    const float* dx_w = (const float*)d_in[5];
    const float* dx_b = (const float*)d_in[6];
    const float* t_w  = (const float*)d_in[7];
    const float* t_b  = (const float*)d_in[8];
    const float* y0_w = (const float*)d_in[9];
    const float* y0_b = (const float*)d_in[10];
    const float* y1_w = (const float*)d_in[11];
    const float* y1_b = (const float*)d_in[12];
    const float* pz   = (const float*)d_in[13];
    float* out = (float*)d_out;

    int n_rows = in_sizes[0] / D;            // 1,000,000
    int nc     = in_sizes[3];                // 2^21
    int n_rb = (n_rows + 255) / 256;         // 3907 rows blocks needed
    int n_groups = (n_rb + 7) / 8;           // groups of 8 blocks per role
    int n_job_blocks = n_groups * 8;         // blocks per role

    size_t wb_bytes = (size_t)nc * sizeof(float2);   // 16.8 MB
    if (ws_size >= wb_bytes) {
        float2* wb = (float2*)d_ws;
        cevae_build_wb<<<2048, 256, 0, stream>>>(qz_w, qz_b, wb, nc);
        cevae_fused5_kernel<true><<<n_groups * 16, 256, 0, stream>>>(
            x, t, y, wb, qz_w, qz_b, dx_w, dx_b, t_w, t_b, y0_w, y0_b,
            y1_w, y1_b, pz, out, n_rows, n_job_blocks);
    } else {
        cevae_fused5_kernel<false><<<n_groups * 16, 256, 0, stream>>>(
            x, t, y, nullptr, qz_w, qz_b, dx_w, dx_b, t_w, t_b, y0_w, y0_b,
            y1_w, y1_b, pz, out, n_rows, n_job_blocks);
    }
}